// Round 1
// baseline (2097.250 us; speedup 1.0000x reference)
//
#include <hip/hip_runtime.h>

// DecoderStack: B=4,T=1024,D=1024,H=16,DK=DV=64,FF=4096
// Faithful quirks: softmax over QUERY axis (column softmax of TxS scores);
// sub_norm(o) = o - mean - std (ddof=1).
// All matmuls in bf16 MFMA (16x16x32), fp32 accumulate.

typedef unsigned short u16;
typedef __bf16 bf16x8 __attribute__((ext_vector_type(8)));
typedef float f32x4 __attribute__((ext_vector_type(4)));

__device__ __forceinline__ u16 f2bf(float f) {
    unsigned int u = __float_as_uint(f);
    u += 0x7fffu + ((u >> 16) & 1u);   // RNE; inputs are finite
    return (u16)(u >> 16);
}
__device__ __forceinline__ float bf2f(u16 b) {
    return __uint_as_float(((unsigned int)b) << 16);
}

// ---------------- converts / packs ----------------

// n must be divisible by 1024*4; one float4 per thread
__global__ __launch_bounds__(256) void convert_f2b_k(const float* __restrict__ in, u16* __restrict__ out) {
    long i = (long)blockIdx.x * 256 + threadIdx.x;
    float4 v = reinterpret_cast<const float4*>(in)[i];
    ushort4 o;
    o.x = f2bf(v.x); o.y = f2bf(v.y); o.z = f2bf(v.z); o.w = f2bf(v.w);
    reinterpret_cast<ushort4*>(out)[i] = o;
}

// out[p][r][q] = in[p][q][r]  (fp32 -> bf16). Coalesced writes, strided reads.
__global__ __launch_bounds__(256) void pack_perm_k(const float* __restrict__ in, u16* __restrict__ out,
                                                   int Q, int R) {
    long idx = (long)blockIdx.x * 256 + threadIdx.x;
    long q = idx % Q;
    long t = idx / Q;
    long r = t % R;
    long p = t / R;
    out[idx] = f2bf(in[(p * Q + q) * R + r]);
}

// 64x64 tiled bf16 transpose: out[c][r] = in[r][c], batched over z
__global__ __launch_bounds__(256) void transpose_k(const u16* __restrict__ in, long ld_in, long z_in,
                                                   u16* __restrict__ out, long ld_out, long z_out) {
    __shared__ u16 tile[64][66];   // +2 pad: conflict-free column reads for 2B elems
    const u16* inz = in + (long)blockIdx.z * z_in;
    u16* outz = out + (long)blockIdx.z * z_out;
    int r0 = blockIdx.y * 64;
    int c0 = blockIdx.x * 64;
    int tx = threadIdx.x & 63, ty = threadIdx.x >> 6;
    #pragma unroll
    for (int i = 0; i < 64; i += 4)
        tile[ty + i][tx] = inz[(long)(r0 + ty + i) * ld_in + c0 + tx];
    __syncthreads();
    #pragma unroll
    for (int i = 0; i < 64; i += 4)
        outz[(long)(c0 + ty + i) * ld_out + r0 + tx] = tile[tx][ty + i];
}

// ---------------- GEMM: C[M][N] = alpha * A[M][K] x Bt[N][K]^T (+bias/relu) ----------------
// A, Bt bf16 row-major with arbitrary row strides; C fp32 or bf16.
// Batched over blockIdx.z: z = zo*zin + zi, offsets (elements) applied per operand.
// EPI: 0 none, 1 +bias then relu, 2 +bias.
template<int BM, int BN, int BK, int WM, int WN, int OUT_BF16, int EPI>
__global__ __launch_bounds__(256) void gemm_k(
    const u16* __restrict__ A, long lda, long a_zin, long a_zout,
    const u16* __restrict__ B, long ldb, long b_zin, long b_zout,
    void* __restrict__ Cv, long ldc, long c_zin, long c_zout,
    int zin, int K, float alpha, const float* __restrict__ bias)
{
    static_assert(BK == 64, "staging assumes BK=64");
    constexpr int WTM = BM / WM;
    constexpr int WTN = BN / WN;
    constexpr int TM = WTM / 16;
    constexpr int TN = WTN / 16;
    __shared__ __align__(16) u16 As[BM * BK];
    __shared__ __align__(16) u16 Bs[BN * BK];

    int z = blockIdx.z;
    int zi = z % zin, zo = z / zin;
    A += (long)zi * a_zin + (long)zo * a_zout;
    B += (long)zi * b_zin + (long)zo * b_zout;
    long coff = (long)zi * c_zin + (long)zo * c_zout;

    int tid = threadIdx.x;
    int lane = tid & 63;
    int wave = tid >> 6;
    int wm = wave / WN, wn = wave % WN;
    long bm0 = (long)blockIdx.y * BM, bn0 = (long)blockIdx.x * BN;

    f32x4 acc[TM][TN];
    #pragma unroll
    for (int i = 0; i < TM; ++i)
        #pragma unroll
        for (int j = 0; j < TN; ++j) {
            acc[i][j][0] = 0.f; acc[i][j][1] = 0.f;
            acc[i][j][2] = 0.f; acc[i][j][3] = 0.f;
        }

    int r16 = lane & 15;
    int kq = (lane >> 4) * 8;           // A/B frag k-offset: quad*8

    constexpr int AIT = BM * BK / 8 / 256;   // 16B chunks per thread for A tile
    constexpr int BIT = BN * BK / 8 / 256;

    for (int k0 = 0; k0 < K; k0 += BK) {
        #pragma unroll
        for (int t = 0; t < AIT; ++t) {
            int c = tid + t * 256;
            int row = c >> 3;            // 8 chunks (of 8 bf16) per 64-elem row
            int col = (c & 7) * 8;
            *reinterpret_cast<int4*>(&As[row * BK + col]) =
                *reinterpret_cast<const int4*>(&A[(bm0 + row) * lda + k0 + col]);
        }
        #pragma unroll
        for (int t = 0; t < BIT; ++t) {
            int c = tid + t * 256;
            int row = c >> 3;
            int col = (c & 7) * 8;
            *reinterpret_cast<int4*>(&Bs[row * BK + col]) =
                *reinterpret_cast<const int4*>(&B[(bn0 + row) * ldb + k0 + col]);
        }
        __syncthreads();
        #pragma unroll
        for (int kk = 0; kk < BK; kk += 32) {
            bf16x8 av[TM], bv[TN];
            #pragma unroll
            for (int i = 0; i < TM; ++i)
                av[i] = *reinterpret_cast<const bf16x8*>(&As[(wm * WTM + i * 16 + r16) * BK + kk + kq]);
            #pragma unroll
            for (int j = 0; j < TN; ++j)
                bv[j] = *reinterpret_cast<const bf16x8*>(&Bs[(wn * WTN + j * 16 + r16) * BK + kk + kq]);
            #pragma unroll
            for (int i = 0; i < TM; ++i)
                #pragma unroll
                for (int j = 0; j < TN; ++j)
                    acc[i][j] = __builtin_amdgcn_mfma_f32_16x16x32_bf16(av[i], bv[j], acc[i][j], 0, 0, 0);
        }
        __syncthreads();
    }

    // epilogue: C/D frag is col=lane&15, row=quad*4+reg (verified m89/m91)
    int rb = (lane >> 4) * 4;
    #pragma unroll
    for (int i = 0; i < TM; ++i) {
        #pragma unroll
        for (int j = 0; j < TN; ++j) {
            long col = bn0 + wn * WTN + j * 16 + r16;
            float bsv = (EPI != 0) ? bias[col] : 0.f;
            #pragma unroll
            for (int r = 0; r < 4; ++r) {
                long row = bm0 + wm * WTM + i * 16 + rb + r;
                float v = acc[i][j][r] * alpha;
                if (EPI == 1) { v += bsv; v = v > 0.f ? v : 0.f; }
                else if (EPI == 2) { v += bsv; }
                long idx = coff + row * ldc + col;
                if (OUT_BF16) reinterpret_cast<u16*>(Cv)[idx] = f2bf(v);
                else          reinterpret_cast<float*>(Cv)[idx] = v;
            }
        }
    }
}

// ---------------- column softmax over t (query axis), P is [H][T][S] bf16, in place ----------------
__global__ __launch_bounds__(256) void col_softmax_k(u16* __restrict__ P) {
    int s = blockIdx.x * 256 + threadIdx.x;
    u16* Ph = P + (long)blockIdx.y * (1024 * 1024) + s;
    float m = -1e30f, l = 0.f;
    for (int t = 0; t < 1024; ++t) {
        float v = bf2f(Ph[t * 1024]);
        float mn = fmaxf(m, v);
        l = l * __expf(m - mn) + __expf(v - mn);
        m = mn;
    }
    float inv = 1.f / l;
    for (int t = 0; t < 1024; ++t) {
        float v = bf2f(Ph[t * 1024]);
        Ph[t * 1024] = f2bf(__expf(v - m) * inv);
    }
}

// ---------------- out = (a+b) - mean - std (ddof=1), rows of 1024, one block per row ----------------
__global__ __launch_bounds__(256) void add_subnorm_k(const float* __restrict__ a, const float* __restrict__ b,
                                                     float* __restrict__ out) {
    __shared__ float sm[8];
    long row = blockIdx.x;
    int tid = threadIdx.x;
    float4 av = reinterpret_cast<const float4*>(a + row * 1024)[tid];
    float4 bv = reinterpret_cast<const float4*>(b + row * 1024)[tid];
    float x0 = av.x + bv.x, x1 = av.y + bv.y, x2 = av.z + bv.z, x3 = av.w + bv.w;
    float s = x0 + x1 + x2 + x3;
    for (int o = 32; o > 0; o >>= 1) s += __shfl_down(s, o, 64);
    int lane = tid & 63, w = tid >> 6;
    if (lane == 0) sm[w] = s;
    __syncthreads();
    float mean = (sm[0] + sm[1] + sm[2] + sm[3]) * (1.f / 1024.f);
    float d0 = x0 - mean, d1 = x1 - mean, d2 = x2 - mean, d3 = x3 - mean;
    float q = d0 * d0 + d1 * d1 + d2 * d2 + d3 * d3;
    for (int o = 32; o > 0; o >>= 1) q += __shfl_down(q, o, 64);
    if (lane == 0) sm[w + 4] = q;
    __syncthreads();
    float sd = sqrtf((sm[4] + sm[5] + sm[6] + sm[7]) * (1.f / 1023.f));
    float4 ov;
    ov.x = d0 - sd; ov.y = d1 - sd; ov.z = d2 - sd; ov.w = d3 - sd;
    reinterpret_cast<float4*>(out + row * 1024)[tid] = ov;
}

// ---------------- launcher ----------------

extern "C" void kernel_launch(void* const* d_in, const int* in_sizes, int n_in,
                              void* d_out, int out_size, void* d_ws, size_t ws_size,
                              hipStream_t stream) {
    (void)in_sizes; (void)n_in; (void)out_size; (void)ws_size;
    const float* xf   = (const float*)d_in[0];
    const float* yf   = (const float*)d_in[1];
    const float* Wq1  = (const float*)d_in[2];
    const float* Wk1  = (const float*)d_in[3];
    const float* Wv1  = (const float*)d_in[4];
    const float* Wo1  = (const float*)d_in[5];
    const float* Wq2  = (const float*)d_in[6];
    const float* Wk2  = (const float*)d_in[7];
    const float* Wv2  = (const float*)d_in[8];
    const float* Wo2  = (const float*)d_in[9];
    const float* W_in = (const float*)d_in[10];
    const float* b_in = (const float*)d_in[11];
    const float* W_out= (const float*)d_in[12];
    const float* b_out= (const float*)d_in[13];

    // workspace layout (needs ~159.4 MB)
    char* p = (char*)d_ws;
    auto alloc = [&](size_t bytes) { char* r = p; p += bytes; return r; };
    u16*   yb    = (u16*)alloc(8388608);    // y bf16 (4096x1024)
    u16*   xb    = (u16*)alloc(8388608);    // x bf16
    u16*   W1cat = (u16*)alloc(6291456);    // [Wq1|Wk1|Wv1]^T-packed (3072 x 1024)
    u16*   Wq2t  = (u16*)alloc(2097152);    // (1024 x 1024)
    u16*   Wkv2t = (u16*)alloc(4194304);    // (2048 x 1024)
    u16*   Wo1t  = (u16*)alloc(2097152);
    u16*   Wo2t  = (u16*)alloc(2097152);
    u16*   Winb  = (u16*)alloc(8388608);    // W_in as-is (4096 x 1024) = Bt layout
    u16*   Woutb = (u16*)alloc(8388608);    // W_out as-is (1024 x 4096) = Bt layout
    u16*   QKV   = (u16*)alloc(25165824);   // (4096 x 3072) bf16: [Q|K|V] per (b,t), n=h*64+k
    u16*   Vt    = (u16*)alloc(8388608);    // per b: (1024 hv x 1024 s)
    u16*   Pb    = (u16*)alloc(33554432);   // per b: [16][1024][1024] bf16; reused as FFN hidden
    u16*   part  = (u16*)alloc(8388608);    // attn partial (4096 x 1024) bf16
    float* gout  = (float*)alloc(16777216); // fp32 gemm out (mha1/mha2/ff)
    float* out1  = (float*)alloc(16777216);
    float* out2d = (float*)d_out;           // out2 lives in d_out

    // ---- converts + weight packs ----
    convert_f2b_k<<<4096, 256, 0, stream>>>(yf, yb);
    convert_f2b_k<<<4096, 256, 0, stream>>>(xf, xb);
    pack_perm_k<<<4096, 256, 0, stream>>>(Wq1, W1cat,           1024, 64);
    pack_perm_k<<<4096, 256, 0, stream>>>(Wk1, W1cat + 1048576, 1024, 64);
    pack_perm_k<<<4096, 256, 0, stream>>>(Wv1, W1cat + 2097152, 1024, 64);
    pack_perm_k<<<4096, 256, 0, stream>>>(Wq2, Wq2t,            1024, 64);
    pack_perm_k<<<4096, 256, 0, stream>>>(Wk2, Wkv2t,           1024, 64);
    pack_perm_k<<<4096, 256, 0, stream>>>(Wv2, Wkv2t + 1048576, 1024, 64);
    pack_perm_k<<<4096, 256, 0, stream>>>(Wo1, Wo1t,            1024, 1024);
    pack_perm_k<<<4096, 256, 0, stream>>>(Wo2, Wo2t,            1024, 1024);
    convert_f2b_k<<<4096, 256, 0, stream>>>(W_in,  Winb);
    convert_f2b_k<<<4096, 256, 0, stream>>>(W_out, Woutb);

    // attention core for one MHA (QKV buffer already populated)
    auto run_attention = [&](u16* qkv) {
        // V^T per batch: Vt[b][h*64+v][s]
        transpose_k<<<dim3(16, 16, 4), 256, 0, stream>>>(qkv + 2048, 3072L, 3145728L, Vt, 1024L, 1048576L);
        for (int b = 0; b < 4; ++b) {
            const u16* Qb = qkv + (long)b * 3145728;           // cols 0..1023, +h*64 per z
            const u16* Kb = qkv + (long)b * 3145728 + 1024;    // cols 1024..2047
            // scores[h][t][s] = (Q K^T)/8, bf16
            gemm_k<128,128,64,2,2,1,0><<<dim3(8, 8, 16), 256, 0, stream>>>(
                Qb, 3072L, 64L, 0L, Kb, 3072L, 64L, 0L,
                (void*)Pb, 1024L, 1048576L, 0L, 16, 64, 0.125f, nullptr);
            // softmax over t per (h,s)
            col_softmax_k<<<dim3(4, 16), 256, 0, stream>>>(Pb);
            // partial[b,t,h*64+v] = sum_s P[t][s] * Vt[h*64+v][s]
            gemm_k<128,64,64,2,2,1,0><<<dim3(1, 8, 16), 256, 0, stream>>>(
                Pb, 1024L, 1048576L, 0L, Vt + (long)b * 1048576, 1024L, 65536L, 0L,
                (void*)(part + (long)b * 1048576), 1024L, 64L, 0L, 16, 1024, 1.0f, nullptr);
        }
    };

    // ---- MHA1 (self-attn on y) ----
    gemm_k<128,128,64,2,2,1,0><<<dim3(24, 32, 1), 256, 0, stream>>>(
        yb, 1024L, 0L, 0L, W1cat, 1024L, 0L, 0L, (void*)QKV, 3072L, 0L, 0L, 1, 1024, 1.0f, nullptr);
    run_attention(QKV);
    gemm_k<128,128,64,2,2,0,0><<<dim3(8, 32, 1), 256, 0, stream>>>(
        part, 1024L, 0L, 0L, Wo1t, 1024L, 0L, 0L, (void*)gout, 1024L, 0L, 0L, 1, 1024, 1.0f, nullptr);
    add_subnorm_k<<<4096, 256, 0, stream>>>(gout, yf, out1);

    // ---- MHA2 (q from y, k/v from x) ----
    gemm_k<128,128,64,2,2,1,0><<<dim3(8, 32, 1), 256, 0, stream>>>(
        yb, 1024L, 0L, 0L, Wq2t, 1024L, 0L, 0L, (void*)QKV, 3072L, 0L, 0L, 1, 1024, 1.0f, nullptr);
    gemm_k<128,128,64,2,2,1,0><<<dim3(16, 32, 1), 256, 0, stream>>>(
        xb, 1024L, 0L, 0L, Wkv2t, 1024L, 0L, 0L, (void*)(QKV + 1024), 3072L, 0L, 0L, 1, 1024, 1.0f, nullptr);
    run_attention(QKV);
    gemm_k<128,128,64,2,2,0,0><<<dim3(8, 32, 1), 256, 0, stream>>>(
        part, 1024L, 0L, 0L, Wo2t, 1024L, 0L, 0L, (void*)gout, 1024L, 0L, 0L, 1, 1024, 1.0f, nullptr);
    add_subnorm_k<<<4096, 256, 0, stream>>>(gout, out1, out2d);

    // ---- FFN on y (hidden reuses Pb: 4096x4096 bf16) ----
    gemm_k<128,128,64,2,2,1,1><<<dim3(32, 32, 1), 256, 0, stream>>>(
        yb, 1024L, 0L, 0L, Winb, 1024L, 0L, 0L, (void*)Pb, 4096L, 0L, 0L, 1, 1024, 1.0f, b_in);
    gemm_k<128,128,64,2,2,0,2><<<dim3(8, 32, 1), 256, 0, stream>>>(
        Pb, 4096L, 0L, 0L, Woutb, 4096L, 0L, 0L, (void*)gout, 1024L, 0L, 0L, 1, 4096, 1.0f, b_out);
    add_subnorm_k<<<4096, 256, 0, stream>>>(gout, (const float*)d_out, (float*)d_out);
}

// Round 2
// 1082.692 us; speedup vs baseline: 1.9371x; 1.9371x over previous
//
#include <hip/hip_runtime.h>

// DecoderStack: B=4,T=1024,D=1024,H=16,DK=DV=64,FF=4096
// Faithful quirks: softmax over QUERY axis (handled as ROW softmax on S^T);
// sub_norm(o) = o - mean - std (ddof=1).
// All matmuls in bf16 MFMA (16x16x32), fp32 accumulate.

typedef unsigned short u16;
typedef __bf16 bf16x8 __attribute__((ext_vector_type(8)));
typedef float f32x4 __attribute__((ext_vector_type(4)));

__device__ __forceinline__ u16 f2bf(float f) {
    unsigned int u = __float_as_uint(f);
    u += 0x7fffu + ((u >> 16) & 1u);   // RNE; inputs are finite
    return (u16)(u >> 16);
}
__device__ __forceinline__ float bf2f(u16 b) {
    return __uint_as_float(((unsigned int)b) << 16);
}

// ---------------- converts / packs ----------------

// n must be divisible by 1024*4; one float4 per thread
__global__ __launch_bounds__(256) void convert_f2b_k(const float* __restrict__ in, u16* __restrict__ out) {
    long i = (long)blockIdx.x * 256 + threadIdx.x;
    float4 v = reinterpret_cast<const float4*>(in)[i];
    ushort4 o;
    o.x = f2bf(v.x); o.y = f2bf(v.y); o.z = f2bf(v.z); o.w = f2bf(v.w);
    reinterpret_cast<ushort4*>(out)[i] = o;
}

// out[p][r][q] = in[p][q][r]  (fp32 -> bf16). Coalesced writes, strided reads.
__global__ __launch_bounds__(256) void pack_perm_k(const float* __restrict__ in, u16* __restrict__ out,
                                                   int Q, int R) {
    long idx = (long)blockIdx.x * 256 + threadIdx.x;
    long q = idx % Q;
    long t = idx / Q;
    long r = t % R;
    long p = t / R;
    out[idx] = f2bf(in[(p * Q + q) * R + r]);
}

// 64x64 tiled bf16 transpose: out[c][r] = in[r][c], batched over z
__global__ __launch_bounds__(256) void transpose_k(const u16* __restrict__ in, long ld_in, long z_in,
                                                   u16* __restrict__ out, long ld_out, long z_out) {
    __shared__ u16 tile[64][66];   // +2 pad: conflict-free column reads for 2B elems
    const u16* inz = in + (long)blockIdx.z * z_in;
    u16* outz = out + (long)blockIdx.z * z_out;
    int r0 = blockIdx.y * 64;
    int c0 = blockIdx.x * 64;
    int tx = threadIdx.x & 63, ty = threadIdx.x >> 6;
    #pragma unroll
    for (int i = 0; i < 64; i += 4)
        tile[ty + i][tx] = inz[(long)(r0 + ty + i) * ld_in + c0 + tx];
    __syncthreads();
    #pragma unroll
    for (int i = 0; i < 64; i += 4)
        outz[(long)(c0 + ty + i) * ld_out + r0 + tx] = tile[tx][ty + i];
}

// ---------------- GEMM: C[M][N] = alpha * A[M][K] x Bt[N][K]^T (+bias/relu) ----------------
// A, Bt bf16 row-major with arbitrary row strides; C fp32 or bf16.
// Batched over blockIdx.z: z = zo*zin + zi, offsets (elements) applied per operand.
// EPI: 0 none, 1 +bias then relu, 2 +bias.
template<int BM, int BN, int BK, int WM, int WN, int OUT_BF16, int EPI>
__global__ __launch_bounds__(256) void gemm_k(
    const u16* __restrict__ A, long lda, long a_zin, long a_zout,
    const u16* __restrict__ B, long ldb, long b_zin, long b_zout,
    void* __restrict__ Cv, long ldc, long c_zin, long c_zout,
    int zin, int K, float alpha, const float* __restrict__ bias)
{
    static_assert(BK == 64, "staging assumes BK=64");
    constexpr int WTM = BM / WM;
    constexpr int WTN = BN / WN;
    constexpr int TM = WTM / 16;
    constexpr int TN = WTN / 16;
    __shared__ __align__(16) u16 As[BM * BK];
    __shared__ __align__(16) u16 Bs[BN * BK];

    int z = blockIdx.z;
    int zi = z % zin, zo = z / zin;
    A += (long)zi * a_zin + (long)zo * a_zout;
    B += (long)zi * b_zin + (long)zo * b_zout;
    long coff = (long)zi * c_zin + (long)zo * c_zout;

    int tid = threadIdx.x;
    int lane = tid & 63;
    int wave = tid >> 6;
    int wm = wave / WN, wn = wave % WN;
    long bm0 = (long)blockIdx.y * BM, bn0 = (long)blockIdx.x * BN;

    f32x4 acc[TM][TN];
    #pragma unroll
    for (int i = 0; i < TM; ++i)
        #pragma unroll
        for (int j = 0; j < TN; ++j) {
            acc[i][j][0] = 0.f; acc[i][j][1] = 0.f;
            acc[i][j][2] = 0.f; acc[i][j][3] = 0.f;
        }

    int r16 = lane & 15;
    int kq = (lane >> 4) * 8;           // A/B frag k-offset: quad*8

    constexpr int AIT = BM * BK / 8 / 256;   // 16B chunks per thread for A tile
    constexpr int BIT = BN * BK / 8 / 256;

    for (int k0 = 0; k0 < K; k0 += BK) {
        #pragma unroll
        for (int t = 0; t < AIT; ++t) {
            int c = tid + t * 256;
            int row = c >> 3;            // 8 chunks (of 8 bf16) per 64-elem row
            int col = (c & 7) * 8;
            *reinterpret_cast<int4*>(&As[row * BK + col]) =
                *reinterpret_cast<const int4*>(&A[(bm0 + row) * lda + k0 + col]);
        }
        #pragma unroll
        for (int t = 0; t < BIT; ++t) {
            int c = tid + t * 256;
            int row = c >> 3;
            int col = (c & 7) * 8;
            *reinterpret_cast<int4*>(&Bs[row * BK + col]) =
                *reinterpret_cast<const int4*>(&B[(bn0 + row) * ldb + k0 + col]);
        }
        __syncthreads();
        #pragma unroll
        for (int kk = 0; kk < BK; kk += 32) {
            bf16x8 av[TM], bv[TN];
            #pragma unroll
            for (int i = 0; i < TM; ++i)
                av[i] = *reinterpret_cast<const bf16x8*>(&As[(wm * WTM + i * 16 + r16) * BK + kk + kq]);
            #pragma unroll
            for (int j = 0; j < TN; ++j)
                bv[j] = *reinterpret_cast<const bf16x8*>(&Bs[(wn * WTN + j * 16 + r16) * BK + kk + kq]);
            #pragma unroll
            for (int i = 0; i < TM; ++i)
                #pragma unroll
                for (int j = 0; j < TN; ++j)
                    acc[i][j] = __builtin_amdgcn_mfma_f32_16x16x32_bf16(av[i], bv[j], acc[i][j], 0, 0, 0);
        }
        __syncthreads();
    }

    // epilogue: C/D frag is col=lane&15, row=quad*4+reg (verified m89/m91)
    int rb = (lane >> 4) * 4;
    #pragma unroll
    for (int i = 0; i < TM; ++i) {
        #pragma unroll
        for (int j = 0; j < TN; ++j) {
            long col = bn0 + wn * WTN + j * 16 + r16;
            float bsv = (EPI != 0) ? bias[col] : 0.f;
            #pragma unroll
            for (int r = 0; r < 4; ++r) {
                long row = bm0 + wm * WTM + i * 16 + rb + r;
                float v = acc[i][j][r] * alpha;
                if (EPI == 1) { v += bsv; v = v > 0.f ? v : 0.f; }
                else if (EPI == 2) { v += bsv; }
                long idx = coff + row * ldc + col;
                if (OUT_BF16) reinterpret_cast<u16*>(Cv)[idx] = f2bf(v);
                else          reinterpret_cast<float*>(Cv)[idx] = v;
            }
        }
    }
}

// ---------------- row softmax: P is rows of 1024 bf16, one wave per row, in place ----------------
__global__ __launch_bounds__(256) void row_softmax_k(u16* __restrict__ P) {
    long row = (long)blockIdx.x * 4 + (threadIdx.x >> 6);
    int lane = threadIdx.x & 63;
    u16* r = P + row * 1024 + lane * 8;
    u16 buf[16];
    *reinterpret_cast<int4*>(buf)     = *reinterpret_cast<const int4*>(r);
    *reinterpret_cast<int4*>(buf + 8) = *reinterpret_cast<const int4*>(r + 512);
    float v[16];
    float m = -1e30f;
    #pragma unroll
    for (int i = 0; i < 16; ++i) { v[i] = bf2f(buf[i]); m = fmaxf(m, v[i]); }
    #pragma unroll
    for (int o = 32; o > 0; o >>= 1) m = fmaxf(m, __shfl_xor(m, o, 64));
    float l = 0.f;
    #pragma unroll
    for (int i = 0; i < 16; ++i) { v[i] = __expf(v[i] - m); l += v[i]; }
    #pragma unroll
    for (int o = 32; o > 0; o >>= 1) l += __shfl_xor(l, o, 64);
    float inv = 1.f / l;
    #pragma unroll
    for (int i = 0; i < 16; ++i) buf[i] = f2bf(v[i] * inv);
    *reinterpret_cast<int4*>(r)       = *reinterpret_cast<const int4*>(buf);
    *reinterpret_cast<int4*>(r + 512) = *reinterpret_cast<const int4*>(buf + 8);
}

// ---------------- out = (a+b) - mean - std (ddof=1), rows of 1024, one block per row ----------------
__global__ __launch_bounds__(256) void add_subnorm_k(const float* __restrict__ a, const float* __restrict__ b,
                                                     float* __restrict__ out) {
    __shared__ float sm[8];
    long row = blockIdx.x;
    int tid = threadIdx.x;
    float4 av = reinterpret_cast<const float4*>(a + row * 1024)[tid];
    float4 bv = reinterpret_cast<const float4*>(b + row * 1024)[tid];
    float x0 = av.x + bv.x, x1 = av.y + bv.y, x2 = av.z + bv.z, x3 = av.w + bv.w;
    float s = x0 + x1 + x2 + x3;
    for (int o = 32; o > 0; o >>= 1) s += __shfl_down(s, o, 64);
    int lane = tid & 63, w = tid >> 6;
    if (lane == 0) sm[w] = s;
    __syncthreads();
    float mean = (sm[0] + sm[1] + sm[2] + sm[3]) * (1.f / 1024.f);
    float d0 = x0 - mean, d1 = x1 - mean, d2 = x2 - mean, d3 = x3 - mean;
    float q = d0 * d0 + d1 * d1 + d2 * d2 + d3 * d3;
    for (int o = 32; o > 0; o >>= 1) q += __shfl_down(q, o, 64);
    if (lane == 0) sm[w + 4] = q;
    __syncthreads();
    float sd = sqrtf((sm[4] + sm[5] + sm[6] + sm[7]) * (1.f / 1023.f));
    float4 ov;
    ov.x = d0 - sd; ov.y = d1 - sd; ov.z = d2 - sd; ov.w = d3 - sd;
    reinterpret_cast<float4*>(out + row * 1024)[tid] = ov;
}

// ---------------- launcher ----------------

extern "C" void kernel_launch(void* const* d_in, const int* in_sizes, int n_in,
                              void* d_out, int out_size, void* d_ws, size_t ws_size,
                              hipStream_t stream) {
    (void)in_sizes; (void)n_in; (void)out_size; (void)ws_size;
    const float* xf   = (const float*)d_in[0];
    const float* yf   = (const float*)d_in[1];
    const float* Wq1  = (const float*)d_in[2];
    const float* Wk1  = (const float*)d_in[3];
    const float* Wv1  = (const float*)d_in[4];
    const float* Wo1  = (const float*)d_in[5];
    const float* Wq2  = (const float*)d_in[6];
    const float* Wk2  = (const float*)d_in[7];
    const float* Wv2  = (const float*)d_in[8];
    const float* Wo2  = (const float*)d_in[9];
    const float* W_in = (const float*)d_in[10];
    const float* b_in = (const float*)d_in[11];
    const float* W_out= (const float*)d_in[12];
    const float* b_out= (const float*)d_in[13];

    // workspace layout (needs ~193 MB)
    char* p = (char*)d_ws;
    auto alloc = [&](size_t bytes) { char* r = p; p += bytes; return r; };
    u16*   yb    = (u16*)alloc(8388608);    // y bf16 (4096x1024)
    u16*   xb    = (u16*)alloc(8388608);    // x bf16
    u16*   W1cat = (u16*)alloc(6291456);    // [Wq1|Wk1|Wv1]^T-packed (3072 x 1024)
    u16*   Wq2t  = (u16*)alloc(2097152);    // (1024 x 1024)
    u16*   Wkv2t = (u16*)alloc(4194304);    // (2048 x 1024)
    u16*   Wo1t  = (u16*)alloc(2097152);
    u16*   Wo2t  = (u16*)alloc(2097152);
    u16*   Winb  = (u16*)alloc(8388608);    // W_in as-is (4096 x 1024) = Bt layout
    u16*   Woutb = (u16*)alloc(8388608);    // W_out as-is (1024 x 4096) = Bt layout
    u16*   QKV   = (u16*)alloc(25165824);   // (4096 x 3072) bf16: [Q|K|V] per (b,t), n=h*64+k
    u16*   Vt    = (u16*)alloc(8388608);    // per b: (1024 hv x 1024 s)
    u16*   Pb    = (u16*)alloc(33554432);   // per b: St [16][1024 s][1024 t] bf16; reused as FFN hidden
    u16*   Pc    = (u16*)alloc(33554432);   // per b: P  [16][1024 t][1024 s] bf16 (transposed)
    u16*   part  = (u16*)alloc(8388608);    // attn partial (4096 x 1024) bf16
    float* gout  = (float*)alloc(16777216); // fp32 gemm out (mha1/mha2/ff)
    float* out1  = (float*)alloc(16777216);
    float* out2d = (float*)d_out;           // out2 lives in d_out

    // ---- converts + weight packs ----
    convert_f2b_k<<<4096, 256, 0, stream>>>(yf, yb);
    convert_f2b_k<<<4096, 256, 0, stream>>>(xf, xb);
    pack_perm_k<<<4096, 256, 0, stream>>>(Wq1, W1cat,           1024, 64);
    pack_perm_k<<<4096, 256, 0, stream>>>(Wk1, W1cat + 1048576, 1024, 64);
    pack_perm_k<<<4096, 256, 0, stream>>>(Wv1, W1cat + 2097152, 1024, 64);
    pack_perm_k<<<4096, 256, 0, stream>>>(Wq2, Wq2t,            1024, 64);
    pack_perm_k<<<4096, 256, 0, stream>>>(Wk2, Wkv2t,           1024, 64);
    pack_perm_k<<<4096, 256, 0, stream>>>(Wv2, Wkv2t + 1048576, 1024, 64);
    pack_perm_k<<<4096, 256, 0, stream>>>(Wo1, Wo1t,            1024, 1024);
    pack_perm_k<<<4096, 256, 0, stream>>>(Wo2, Wo2t,            1024, 1024);
    convert_f2b_k<<<4096, 256, 0, stream>>>(W_in,  Winb);
    convert_f2b_k<<<4096, 256, 0, stream>>>(W_out, Woutb);

    // attention core for one MHA (QKV buffer already populated)
    auto run_attention = [&](u16* qkv) {
        // V^T per batch: Vt[b][h*64+v][s]
        transpose_k<<<dim3(16, 16, 4), 256, 0, stream>>>(qkv + 2048, 3072L, 3145728L, Vt, 1024L, 1048576L);
        for (int b = 0; b < 4; ++b) {
            const u16* Qb = qkv + (long)b * 3145728;           // cols 0..1023, +h*64 per z
            const u16* Kb = qkv + (long)b * 3145728 + 1024;    // cols 1024..2047
            // St[h][s][t] = (K Q^T)/8, bf16  (operands swapped: softmax axis becomes rows)
            gemm_k<128,128,64,2,2,1,0><<<dim3(8, 8, 16), 256, 0, stream>>>(
                Kb, 3072L, 64L, 0L, Qb, 3072L, 64L, 0L,
                (void*)Pb, 1024L, 1048576L, 0L, 16, 64, 0.125f, nullptr);
            // softmax over t: row softmax on St, one wave per row
            row_softmax_k<<<4096, 256, 0, stream>>>(Pb);
            // transpose St -> P[h][t][s]
            transpose_k<<<dim3(16, 16, 16), 256, 0, stream>>>(Pb, 1024L, 1048576L, Pc, 1024L, 1048576L);
            // partial[b,t,h*64+v] = sum_s P[t][s] * Vt[h*64+v][s]
            gemm_k<64,64,64,2,2,1,0><<<dim3(1, 16, 16), 256, 0, stream>>>(
                Pc, 1024L, 1048576L, 0L, Vt + (long)b * 1048576, 1024L, 65536L, 0L,
                (void*)(part + (long)b * 1048576), 1024L, 64L, 0L, 16, 1024, 1.0f, nullptr);
        }
    };

    // ---- MHA1 (self-attn on y) ----
    gemm_k<128,128,64,2,2,1,0><<<dim3(24, 32, 1), 256, 0, stream>>>(
        yb, 1024L, 0L, 0L, W1cat, 1024L, 0L, 0L, (void*)QKV, 3072L, 0L, 0L, 1, 1024, 1.0f, nullptr);
    run_attention(QKV);
    gemm_k<128,128,64,2,2,0,0><<<dim3(8, 32, 1), 256, 0, stream>>>(
        part, 1024L, 0L, 0L, Wo1t, 1024L, 0L, 0L, (void*)gout, 1024L, 0L, 0L, 1, 1024, 1.0f, nullptr);
    add_subnorm_k<<<4096, 256, 0, stream>>>(gout, yf, out1);

    // ---- MHA2 (q from y, k/v from x) ----
    gemm_k<128,128,64,2,2,1,0><<<dim3(8, 32, 1), 256, 0, stream>>>(
        yb, 1024L, 0L, 0L, Wq2t, 1024L, 0L, 0L, (void*)QKV, 3072L, 0L, 0L, 1, 1024, 1.0f, nullptr);
    gemm_k<128,128,64,2,2,1,0><<<dim3(16, 32, 1), 256, 0, stream>>>(
        xb, 1024L, 0L, 0L, Wkv2t, 1024L, 0L, 0L, (void*)(QKV + 1024), 3072L, 0L, 0L, 1, 1024, 1.0f, nullptr);
    run_attention(QKV);
    gemm_k<128,128,64,2,2,0,0><<<dim3(8, 32, 1), 256, 0, stream>>>(
        part, 1024L, 0L, 0L, Wo2t, 1024L, 0L, 0L, (void*)gout, 1024L, 0L, 0L, 1, 1024, 1.0f, nullptr);
    add_subnorm_k<<<4096, 256, 0, stream>>>(gout, out1, out2d);

    // ---- FFN on y (hidden reuses Pb: 4096x4096 bf16) ----
    gemm_k<128,128,64,2,2,1,1><<<dim3(32, 32, 1), 256, 0, stream>>>(
        yb, 1024L, 0L, 0L, Winb, 1024L, 0L, 0L, (void*)Pb, 4096L, 0L, 0L, 1, 1024, 1.0f, b_in);
    gemm_k<128,128,64,2,2,0,2><<<dim3(8, 32, 1), 256, 0, stream>>>(
        Pb, 4096L, 0L, 0L, Woutb, 4096L, 0L, 0L, (void*)gout, 1024L, 0L, 0L, 1, 4096, 1.0f, b_out);
    add_subnorm_k<<<4096, 256, 0, stream>>>(gout, (const float*)d_out, (float*)d_out);
}

// Round 3
// 893.197 us; speedup vs baseline: 2.3480x; 1.2122x over previous
//
#include <hip/hip_runtime.h>

// DecoderStack: B=4,T=1024,D=1024,H=16,DK=DV=64,FF=4096
// Faithful quirks: softmax over QUERY axis (column softmax over t, done as
// two coalesced passes); sub_norm(o) = o - mean - std (ddof=1).
// All matmuls bf16 MFMA 16x16x32, fp32 accumulate, global_load_lds staging.

typedef unsigned short u16;
typedef __bf16 bf16x8 __attribute__((ext_vector_type(8)));
typedef float f32x4 __attribute__((ext_vector_type(4)));

__device__ __forceinline__ u16 f2bf(float f) {
    unsigned int u = __float_as_uint(f);
    u += 0x7fffu + ((u >> 16) & 1u);   // RNE; inputs are finite
    return (u16)(u >> 16);
}
__device__ __forceinline__ float bf2f(u16 b) {
    return __uint_as_float(((unsigned int)b) << 16);
}

typedef __attribute__((address_space(1))) const void* as1cv;
typedef __attribute__((address_space(3))) void* as3v;
// async global->LDS, 16B per lane; lds ptr must be wave-uniform (lane i lands at base+i*16)
__device__ __forceinline__ void gl_lds16(const void* g, void* l) {
    __builtin_amdgcn_global_load_lds((as1cv)g, (as3v)l, 16, 0, 0);
}

// ---------------- converts / packs ----------------

__global__ __launch_bounds__(256) void convert_f2b_k(const float* __restrict__ in, u16* __restrict__ out) {
    long i = (long)blockIdx.x * 256 + threadIdx.x;
    float4 v = reinterpret_cast<const float4*>(in)[i];
    ushort4 o;
    o.x = f2bf(v.x); o.y = f2bf(v.y); o.z = f2bf(v.z); o.w = f2bf(v.w);
    reinterpret_cast<ushort4*>(out)[i] = o;
}

// out[p][r][q] = in[p][q][r]  (fp32 -> bf16)
__global__ __launch_bounds__(256) void pack_perm_k(const float* __restrict__ in, u16* __restrict__ out,
                                                   int Q, int R) {
    long idx = (long)blockIdx.x * 256 + threadIdx.x;
    long q = idx % Q;
    long t = idx / Q;
    long r = t % R;
    long p = t / R;
    out[idx] = f2bf(in[(p * Q + q) * R + r]);
}

// 64x64 tiled bf16 transpose: out[c][r] = in[r][c], batched over z
__global__ __launch_bounds__(256) void transpose_k(const u16* __restrict__ in, long ld_in, long z_in,
                                                   u16* __restrict__ out, long ld_out, long z_out) {
    __shared__ u16 tile[64][66];
    const u16* inz = in + (long)blockIdx.z * z_in;
    u16* outz = out + (long)blockIdx.z * z_out;
    int r0 = blockIdx.y * 64;
    int c0 = blockIdx.x * 64;
    int tx = threadIdx.x & 63, ty = threadIdx.x >> 6;
    #pragma unroll
    for (int i = 0; i < 64; i += 4)
        tile[ty + i][tx] = inz[(long)(r0 + ty + i) * ld_in + c0 + tx];
    __syncthreads();
    #pragma unroll
    for (int i = 0; i < 64; i += 4)
        outz[(long)(c0 + ty + i) * ld_out + r0 + tx] = tile[tx][ty + i];
}

// ---------------- GEMM: C[M][N] = alpha * A[M][K] x Bt[N][K]^T (+bias/relu) ----------------
// global_load_lds staging: tiles live in LDS as [row][64] (128B rows, no pad);
// each wave stages 1KB stripes (8 rows), lane i -> stripe_base + i*16B.
// EPI: 0 none, 1 +bias+relu, 2 +bias.
template<int BM, int BN, int BK, int WM, int WN, int OUT_BF16, int EPI>
__global__ __launch_bounds__(256) void gemm_k(
    const u16* __restrict__ A, long lda, long a_zin, long a_zout,
    const u16* __restrict__ B, long ldb, long b_zin, long b_zout,
    void* __restrict__ Cv, long ldc, long c_zin, long c_zout,
    int zin, int K, float alpha, const float* __restrict__ bias)
{
    static_assert(BK == 64, "staging assumes BK=64");
    static_assert(BM % 8 == 0 && BN % 8 == 0, "stripes are 8 rows");
    constexpr int WTM = BM / WM;
    constexpr int WTN = BN / WN;
    constexpr int TM = WTM / 16;
    constexpr int TN = WTN / 16;
    __shared__ __align__(16) u16 As[BM * BK];
    __shared__ __align__(16) u16 Bs[BN * BK];

    int z = blockIdx.z;
    int zi = z % zin, zo = z / zin;
    A += (long)zi * a_zin + (long)zo * a_zout;
    B += (long)zi * b_zin + (long)zo * b_zout;
    long coff = (long)zi * c_zin + (long)zo * c_zout;

    int tid = threadIdx.x;
    int lane = tid & 63;
    int wave = tid >> 6;
    int wm = wave / WN, wn = wave % WN;
    long bm0 = (long)blockIdx.y * BM, bn0 = (long)blockIdx.x * BN;

    f32x4 acc[TM][TN];
    #pragma unroll
    for (int i = 0; i < TM; ++i)
        #pragma unroll
        for (int j = 0; j < TN; ++j) {
            acc[i][j][0] = 0.f; acc[i][j][1] = 0.f;
            acc[i][j][2] = 0.f; acc[i][j][3] = 0.f;
        }

    int r16 = lane & 15;
    int kq = (lane >> 4) * 8;           // A/B frag k-offset: quad*8
    int l8 = lane >> 3;                 // row within stripe
    int c8 = (lane & 7) * 8;            // col (elements) within row

    constexpr int ASTR = BM / 8;        // 1KB stripes in A tile
    constexpr int BSTR = BN / 8;

    for (int k0 = 0; k0 < K; k0 += BK) {
        #pragma unroll
        for (int s = wave; s < ASTR; s += 4)
            gl_lds16(&A[(bm0 + s * 8 + l8) * lda + k0 + c8], &As[s * 512]);
        #pragma unroll
        for (int s = wave; s < BSTR; s += 4)
            gl_lds16(&B[(bn0 + s * 8 + l8) * ldb + k0 + c8], &Bs[s * 512]);
        __syncthreads();
        #pragma unroll
        for (int kk = 0; kk < BK; kk += 32) {
            bf16x8 av[TM], bv[TN];
            #pragma unroll
            for (int i = 0; i < TM; ++i)
                av[i] = *reinterpret_cast<const bf16x8*>(&As[(wm * WTM + i * 16 + r16) * BK + kk + kq]);
            #pragma unroll
            for (int j = 0; j < TN; ++j)
                bv[j] = *reinterpret_cast<const bf16x8*>(&Bs[(wn * WTN + j * 16 + r16) * BK + kk + kq]);
            #pragma unroll
            for (int i = 0; i < TM; ++i)
                #pragma unroll
                for (int j = 0; j < TN; ++j)
                    acc[i][j] = __builtin_amdgcn_mfma_f32_16x16x32_bf16(av[i], bv[j], acc[i][j], 0, 0, 0);
        }
        __syncthreads();
    }

    // epilogue: C/D frag is col=lane&15, row=quad*4+reg (verified m89/m91)
    int rb = (lane >> 4) * 4;
    #pragma unroll
    for (int i = 0; i < TM; ++i) {
        #pragma unroll
        for (int j = 0; j < TN; ++j) {
            long col = bn0 + wn * WTN + j * 16 + r16;
            float bsv = (EPI != 0) ? bias[col] : 0.f;
            #pragma unroll
            for (int r = 0; r < 4; ++r) {
                long row = bm0 + wm * WTM + i * 16 + rb + r;
                float v = acc[i][j][r] * alpha;
                if (EPI == 1) { v += bsv; v = v > 0.f ? v : 0.f; }
                else if (EPI == 2) { v += bsv; }
                long idx = coff + row * ldc + col;
                if (OUT_BF16) reinterpret_cast<u16*>(Cv)[idx] = f2bf(v);
                else          reinterpret_cast<float*>(Cv)[idx] = v;
            }
        }
    }
}

// ---------------- column softmax over t (two coalesced passes) ----------------
// S: [16][1024][1024] bf16 (one batch). part: [16][16][1024] fp32 partial sums.
// grid dim3(32, 16): blockIdx.x = tc*2+sc (tc: 16 t-chunks of 64, sc: 2 s-halves of 512)
__global__ __launch_bounds__(256) void colpart_k(const u16* __restrict__ S, float* __restrict__ part) {
    int h = blockIdx.y;
    int sc = blockIdx.x & 1;
    int tc = blockIdx.x >> 1;
    int s = sc * 512 + threadIdx.x * 2;
    const u16* base = S + (long)h * 1048576 + (long)tc * 65536 + s;
    float s0 = 0.f, s1 = 0.f;
    #pragma unroll 8
    for (int t = 0; t < 64; ++t) {
        unsigned int u = *reinterpret_cast<const unsigned int*>(base + (long)t * 1024);
        s0 += __expf(bf2f((u16)(u & 0xffff)));
        s1 += __expf(bf2f((u16)(u >> 16)));
    }
    float2 w; w.x = s0; w.y = s1;
    *reinterpret_cast<float2*>(&part[((long)h * 16 + tc) * 1024 + s]) = w;
}

__global__ __launch_bounds__(256) void colnorm_k(u16* __restrict__ S, const float* __restrict__ part) {
    int h = blockIdx.y;
    int sc = blockIdx.x & 1;
    int tc = blockIdx.x >> 1;
    int s = sc * 512 + threadIdx.x * 2;
    float s0 = 0.f, s1 = 0.f;
    #pragma unroll
    for (int i = 0; i < 16; ++i) {
        float2 w = *reinterpret_cast<const float2*>(&part[((long)h * 16 + i) * 1024 + s]);
        s0 += w.x; s1 += w.y;
    }
    float i0 = 1.f / s0, i1 = 1.f / s1;
    u16* base = S + (long)h * 1048576 + (long)tc * 65536 + s;
    #pragma unroll 8
    for (int t = 0; t < 64; ++t) {
        unsigned int u = *reinterpret_cast<unsigned int*>(base + (long)t * 1024);
        float a = __expf(bf2f((u16)(u & 0xffff))) * i0;
        float b = __expf(bf2f((u16)(u >> 16))) * i1;
        *reinterpret_cast<unsigned int*>(base + (long)t * 1024) = ((unsigned)f2bf(b) << 16) | f2bf(a);
    }
}

// ---------------- out = (a+b) - mean - std (ddof=1), rows of 1024 ----------------
__global__ __launch_bounds__(256) void add_subnorm_k(const float* __restrict__ a, const float* __restrict__ b,
                                                     float* __restrict__ out) {
    __shared__ float sm[8];
    long row = blockIdx.x;
    int tid = threadIdx.x;
    float4 av = reinterpret_cast<const float4*>(a + row * 1024)[tid];
    float4 bv = reinterpret_cast<const float4*>(b + row * 1024)[tid];
    float x0 = av.x + bv.x, x1 = av.y + bv.y, x2 = av.z + bv.z, x3 = av.w + bv.w;
    float s = x0 + x1 + x2 + x3;
    for (int o = 32; o > 0; o >>= 1) s += __shfl_down(s, o, 64);
    int lane = tid & 63, w = tid >> 6;
    if (lane == 0) sm[w] = s;
    __syncthreads();
    float mean = (sm[0] + sm[1] + sm[2] + sm[3]) * (1.f / 1024.f);
    float d0 = x0 - mean, d1 = x1 - mean, d2 = x2 - mean, d3 = x3 - mean;
    float q = d0 * d0 + d1 * d1 + d2 * d2 + d3 * d3;
    for (int o = 32; o > 0; o >>= 1) q += __shfl_down(q, o, 64);
    if (lane == 0) sm[w + 4] = q;
    __syncthreads();
    float sd = sqrtf((sm[4] + sm[5] + sm[6] + sm[7]) * (1.f / 1023.f));
    float4 ov;
    ov.x = d0 - sd; ov.y = d1 - sd; ov.z = d2 - sd; ov.w = d3 - sd;
    reinterpret_cast<float4*>(out + row * 1024)[tid] = ov;
}

// ---------------- launcher ----------------

extern "C" void kernel_launch(void* const* d_in, const int* in_sizes, int n_in,
                              void* d_out, int out_size, void* d_ws, size_t ws_size,
                              hipStream_t stream) {
    (void)in_sizes; (void)n_in; (void)out_size; (void)ws_size;
    const float* xf   = (const float*)d_in[0];
    const float* yf   = (const float*)d_in[1];
    const float* Wq1  = (const float*)d_in[2];
    const float* Wk1  = (const float*)d_in[3];
    const float* Wv1  = (const float*)d_in[4];
    const float* Wo1  = (const float*)d_in[5];
    const float* Wq2  = (const float*)d_in[6];
    const float* Wk2  = (const float*)d_in[7];
    const float* Wv2  = (const float*)d_in[8];
    const float* Wo2  = (const float*)d_in[9];
    const float* W_in = (const float*)d_in[10];
    const float* b_in = (const float*)d_in[11];
    const float* W_out= (const float*)d_in[12];
    const float* b_out= (const float*)d_in[13];

    // workspace layout (~161 MB)
    char* p = (char*)d_ws;
    auto alloc = [&](size_t bytes) { char* r = p; p += bytes; return r; };
    u16*   yb    = (u16*)alloc(8388608);    // y bf16 (4096x1024)
    u16*   xb    = (u16*)alloc(8388608);    // x bf16
    u16*   W1cat = (u16*)alloc(6291456);    // [Wq1|Wk1|Wv1]^T-packed (3072 x 1024)
    u16*   Wq2t  = (u16*)alloc(2097152);
    u16*   Wkv2t = (u16*)alloc(4194304);
    u16*   Wo1t  = (u16*)alloc(2097152);
    u16*   Wo2t  = (u16*)alloc(2097152);
    u16*   Winb  = (u16*)alloc(8388608);    // W_in (4096 x 1024) = Bt layout
    u16*   Woutb = (u16*)alloc(8388608);    // W_out (1024 x 4096) = Bt layout
    u16*   QKV   = (u16*)alloc(25165824);   // (4096 x 3072): [Q|K|V] per (b,t)
    u16*   Vt    = (u16*)alloc(8388608);    // per b: (1024 hv x 1024 s)
    u16*   Pb    = (u16*)alloc(33554432);   // per b: S/P [16][1024 t][1024 s]; reused as FFN hidden
    float* csum  = (float*)alloc(1048576);  // colsoftmax partials [16][16][1024] fp32
    u16*   part  = (u16*)alloc(8388608);    // attn partial (4096 x 1024) bf16
    float* gout  = (float*)alloc(16777216); // fp32 gemm out
    float* out1  = (float*)alloc(16777216);
    float* out2d = (float*)d_out;

    // ---- converts + weight packs ----
    convert_f2b_k<<<4096, 256, 0, stream>>>(yf, yb);
    convert_f2b_k<<<4096, 256, 0, stream>>>(xf, xb);
    pack_perm_k<<<4096, 256, 0, stream>>>(Wq1, W1cat,           1024, 64);
    pack_perm_k<<<4096, 256, 0, stream>>>(Wk1, W1cat + 1048576, 1024, 64);
    pack_perm_k<<<4096, 256, 0, stream>>>(Wv1, W1cat + 2097152, 1024, 64);
    pack_perm_k<<<4096, 256, 0, stream>>>(Wq2, Wq2t,            1024, 64);
    pack_perm_k<<<4096, 256, 0, stream>>>(Wk2, Wkv2t,           1024, 64);
    pack_perm_k<<<4096, 256, 0, stream>>>(Wv2, Wkv2t + 1048576, 1024, 64);
    pack_perm_k<<<4096, 256, 0, stream>>>(Wo1, Wo1t,            1024, 1024);
    pack_perm_k<<<4096, 256, 0, stream>>>(Wo2, Wo2t,            1024, 1024);
    convert_f2b_k<<<4096, 256, 0, stream>>>(W_in,  Winb);
    convert_f2b_k<<<4096, 256, 0, stream>>>(W_out, Woutb);

    // attention core for one MHA (QKV buffer already populated)
    auto run_attention = [&](u16* qkv) {
        // V^T per batch: Vt[b][h*64+v][s]
        transpose_k<<<dim3(16, 16, 4), 256, 0, stream>>>(qkv + 2048, 3072L, 3145728L, Vt, 1024L, 1048576L);
        for (int b = 0; b < 4; ++b) {
            const u16* Qb = qkv + (long)b * 3145728;           // cols 0..1023
            const u16* Kb = qkv + (long)b * 3145728 + 1024;    // cols 1024..2047
            // S[h][t][s] = (Q K^T)/8, bf16
            gemm_k<128,128,64,2,2,1,0><<<dim3(8, 8, 16), 256, 0, stream>>>(
                Qb, 3072L, 64L, 0L, Kb, 3072L, 64L, 0L,
                (void*)Pb, 1024L, 1048576L, 0L, 16, 64, 0.125f, nullptr);
            // column softmax over t (two passes, coalesced)
            colpart_k<<<dim3(32, 16), 256, 0, stream>>>(Pb, csum);
            colnorm_k<<<dim3(32, 16), 256, 0, stream>>>(Pb, csum);
            // partial[b,t,h*64+v] = sum_s P[t][s] * Vt[h*64+v][s]
            gemm_k<64,64,64,2,2,1,0><<<dim3(1, 16, 16), 256, 0, stream>>>(
                Pb, 1024L, 1048576L, 0L, Vt + (long)b * 1048576, 1024L, 65536L, 0L,
                (void*)(part + (long)b * 1048576), 1024L, 64L, 0L, 16, 1024, 1.0f, nullptr);
        }
    };

    // ---- MHA1 (self-attn on y) ----
    gemm_k<128,128,64,2,2,1,0><<<dim3(24, 32, 1), 256, 0, stream>>>(
        yb, 1024L, 0L, 0L, W1cat, 1024L, 0L, 0L, (void*)QKV, 3072L, 0L, 0L, 1, 1024, 1.0f, nullptr);
    run_attention(QKV);
    gemm_k<128,64,64,2,2,0,0><<<dim3(16, 32, 1), 256, 0, stream>>>(
        part, 1024L, 0L, 0L, Wo1t, 1024L, 0L, 0L, (void*)gout, 1024L, 0L, 0L, 1, 1024, 1.0f, nullptr);
    add_subnorm_k<<<4096, 256, 0, stream>>>(gout, yf, out1);

    // ---- MHA2 (q from y, k/v from x) ----
    gemm_k<128,64,64,2,2,1,0><<<dim3(16, 32, 1), 256, 0, stream>>>(
        yb, 1024L, 0L, 0L, Wq2t, 1024L, 0L, 0L, (void*)QKV, 3072L, 0L, 0L, 1, 1024, 1.0f, nullptr);
    gemm_k<128,128,64,2,2,1,0><<<dim3(16, 32, 1), 256, 0, stream>>>(
        xb, 1024L, 0L, 0L, Wkv2t, 1024L, 0L, 0L, (void*)(QKV + 1024), 3072L, 0L, 0L, 1, 1024, 1.0f, nullptr);
    run_attention(QKV);
    gemm_k<128,64,64,2,2,0,0><<<dim3(16, 32, 1), 256, 0, stream>>>(
        part, 1024L, 0L, 0L, Wo2t, 1024L, 0L, 0L, (void*)gout, 1024L, 0L, 0L, 1, 1024, 1.0f, nullptr);
    add_subnorm_k<<<4096, 256, 0, stream>>>(gout, out1, out2d);

    // ---- FFN on y (hidden reuses Pb: 4096x4096 bf16) ----
    gemm_k<128,128,64,2,2,1,1><<<dim3(32, 32, 1), 256, 0, stream>>>(
        yb, 1024L, 0L, 0L, Winb, 1024L, 0L, 0L, (void*)Pb, 4096L, 0L, 0L, 1, 1024, 1.0f, b_in);
    gemm_k<128,64,64,2,2,0,2><<<dim3(16, 32, 1), 256, 0, stream>>>(
        Pb, 4096L, 0L, 0L, Woutb, 4096L, 0L, 0L, (void*)gout, 1024L, 0L, 0L, 1, 4096, 1.0f, b_out);
    add_subnorm_k<<<4096, 256, 0, stream>>>(gout, (const float*)d_out, (float*)d_out);
}

// Round 4
// 813.808 us; speedup vs baseline: 2.5771x; 1.0976x over previous
//
#include <hip/hip_runtime.h>

// DecoderStack: B=4,T=1024,D=1024,H=16,DK=DV=64,FF=4096
// Faithful quirks: softmax over QUERY axis (column softmax over t);
// sub_norm(o) = o - mean - std (ddof=1).
// bf16 MFMA 16x16x32, fp32 accumulate, global_load_lds staging,
// XOR-swizzled LDS tiles, XCD-slab block swizzle for K-deep GEMMs.

typedef unsigned short u16;
typedef __bf16 bf16x8 __attribute__((ext_vector_type(8)));
typedef float f32x4 __attribute__((ext_vector_type(4)));

__device__ __forceinline__ u16 f2bf(float f) {
    unsigned int u = __float_as_uint(f);
    u += 0x7fffu + ((u >> 16) & 1u);   // RNE; inputs are finite
    return (u16)(u >> 16);
}
__device__ __forceinline__ float bf2f(u16 b) {
    return __uint_as_float(((unsigned int)b) << 16);
}

typedef __attribute__((address_space(1))) const void* as1cv;
typedef __attribute__((address_space(3))) void* as3v;
// async global->LDS, 16B per lane; lds ptr wave-uniform (lane i -> base+i*16)
__device__ __forceinline__ void gl_lds16(const void* g, void* l) {
    __builtin_amdgcn_global_load_lds((as1cv)g, (as3v)l, 16, 0, 0);
}

// ---------------- converts / packs ----------------

__global__ __launch_bounds__(256) void convert_f2b_k(const float* __restrict__ in, u16* __restrict__ out) {
    long i = (long)blockIdx.x * 256 + threadIdx.x;
    float4 v = reinterpret_cast<const float4*>(in)[i];
    ushort4 o;
    o.x = f2bf(v.x); o.y = f2bf(v.y); o.z = f2bf(v.z); o.w = f2bf(v.w);
    reinterpret_cast<ushort4*>(out)[i] = o;
}

// out[p][r][q] = in[p][q][r]  (fp32 -> bf16)
__global__ __launch_bounds__(256) void pack_perm_k(const float* __restrict__ in, u16* __restrict__ out,
                                                   int Q, int R) {
    long idx = (long)blockIdx.x * 256 + threadIdx.x;
    long q = idx % Q;
    long t = idx / Q;
    long r = t % R;
    long p = t / R;
    out[idx] = f2bf(in[(p * Q + q) * R + r]);
}

// 64x64 tiled bf16 transpose: out[c][r] = in[r][c], batched over z
__global__ __launch_bounds__(256) void transpose_k(const u16* __restrict__ in, long ld_in, long z_in,
                                                   u16* __restrict__ out, long ld_out, long z_out) {
    __shared__ u16 tile[64][66];
    const u16* inz = in + (long)blockIdx.z * z_in;
    u16* outz = out + (long)blockIdx.z * z_out;
    int r0 = blockIdx.y * 64;
    int c0 = blockIdx.x * 64;
    int tx = threadIdx.x & 63, ty = threadIdx.x >> 6;
    #pragma unroll
    for (int i = 0; i < 64; i += 4)
        tile[ty + i][tx] = inz[(long)(r0 + ty + i) * ld_in + c0 + tx];
    __syncthreads();
    #pragma unroll
    for (int i = 0; i < 64; i += 4)
        outz[(long)(c0 + ty + i) * ld_out + r0 + tx] = tile[tx][ty + i];
}

// ---------------- GEMM: C[M][N] = alpha * A[M][K] x Bt[N][K]^T (+bias/relu) ----------------
// LDS tiles XOR-swizzled: LDS[row][slot] holds global 16B-chunk (slot^(row&7)).
// SWZ=0: 3D grid (x=N-tiles, y=M-tiles, z=batch). SWZ=4: 1D grid nx*ny (ny=32,
// ny/8=4=SWZ), XCD-slab mapping: my=(L&7)*4+((L>>3)&3), mx=L>>5.
// EPI: 0 none, 1 +bias+relu, 2 +bias.
template<int BM, int BN, int BK, int WM, int WN, int OUT_BF16, int EPI, int SWZ>
__global__ __launch_bounds__(256) void gemm_k(
    const u16* __restrict__ A, long lda, long a_zin, long a_zout,
    const u16* __restrict__ B, long ldb, long b_zin, long b_zout,
    void* __restrict__ Cv, long ldc, long c_zin, long c_zout,
    int zin, int K, float alpha, const float* __restrict__ bias)
{
    static_assert(BK == 64, "staging assumes BK=64");
    static_assert(BM % 8 == 0 && BN % 8 == 0, "stripes are 8 rows");
    constexpr int WTM = BM / WM;
    constexpr int WTN = BN / WN;
    constexpr int TM = WTM / 16;
    constexpr int TN = WTN / 16;
    __shared__ __align__(16) u16 As[BM * BK];
    __shared__ __align__(16) u16 Bs[BN * BK];

    int bx, by;
    if (SWZ) {
        int L = blockIdx.x;
        by = (L & 7) * SWZ + ((L >> 3) & (SWZ - 1));
        bx = L >> 5;                    // SWZ==4: L / (8*4)
    } else {
        bx = blockIdx.x; by = blockIdx.y;
    }

    int z = SWZ ? 0 : blockIdx.z;
    int zi = z % zin, zo = z / zin;
    A += (long)zi * a_zin + (long)zo * a_zout;
    B += (long)zi * b_zin + (long)zo * b_zout;
    long coff = (long)zi * c_zin + (long)zo * c_zout;

    int tid = threadIdx.x;
    int lane = tid & 63;
    int wave = tid >> 6;
    int wm = wave / WN, wn = wave % WN;
    long bm0 = (long)by * BM, bn0 = (long)bx * BN;

    f32x4 acc[TM][TN];
    #pragma unroll
    for (int i = 0; i < TM; ++i)
        #pragma unroll
        for (int j = 0; j < TN; ++j) {
            acc[i][j][0] = 0.f; acc[i][j][1] = 0.f;
            acc[i][j][2] = 0.f; acc[i][j][3] = 0.f;
        }

    int r16 = lane & 15;
    int quad = lane >> 4;
    int l8 = lane >> 3;                    // stripe row
    int gsw = ((lane & 7) ^ l8) * 8;       // swizzled global col (elements)

    constexpr int ASTR = BM / 8;
    constexpr int BSTR = BN / 8;

    for (int k0 = 0; k0 < K; k0 += BK) {
        #pragma unroll
        for (int s = wave; s < ASTR; s += 4)
            gl_lds16(&A[(bm0 + s * 8 + l8) * lda + k0 + gsw], &As[s * 512]);
        #pragma unroll
        for (int s = wave; s < BSTR; s += 4)
            gl_lds16(&B[(bn0 + s * 8 + l8) * ldb + k0 + gsw], &Bs[s * 512]);
        __syncthreads();
        #pragma unroll
        for (int kk = 0; kk < BK; kk += 32) {
            int cb = (kk >> 3) + quad;     // 16B-chunk wanted
            bf16x8 av[TM], bv[TN];
            #pragma unroll
            for (int i = 0; i < TM; ++i) {
                int r = wm * WTM + i * 16 + r16;
                av[i] = *reinterpret_cast<const bf16x8*>(&As[r * 64 + ((cb ^ (r & 7)) * 8)]);
            }
            #pragma unroll
            for (int j = 0; j < TN; ++j) {
                int r = wn * WTN + j * 16 + r16;
                bv[j] = *reinterpret_cast<const bf16x8*>(&Bs[r * 64 + ((cb ^ (r & 7)) * 8)]);
            }
            #pragma unroll
            for (int i = 0; i < TM; ++i)
                #pragma unroll
                for (int j = 0; j < TN; ++j)
                    acc[i][j] = __builtin_amdgcn_mfma_f32_16x16x32_bf16(av[i], bv[j], acc[i][j], 0, 0, 0);
        }
        __syncthreads();
    }

    // epilogue: C/D frag is col=lane&15, row=quad*4+reg (verified m89/m91)
    int rb = quad * 4;
    #pragma unroll
    for (int i = 0; i < TM; ++i) {
        #pragma unroll
        for (int j = 0; j < TN; ++j) {
            long col = bn0 + wn * WTN + j * 16 + r16;
            float bsv = (EPI != 0) ? bias[col] : 0.f;
            #pragma unroll
            for (int r = 0; r < 4; ++r) {
                long row = bm0 + wm * WTM + i * 16 + rb + r;
                float v = acc[i][j][r] * alpha;
                if (EPI == 1) { v += bsv; v = v > 0.f ? v : 0.f; }
                else if (EPI == 2) { v += bsv; }
                long idx = coff + row * ldc + col;
                if (OUT_BF16) reinterpret_cast<u16*>(Cv)[idx] = f2bf(v);
                else          reinterpret_cast<float*>(Cv)[idx] = v;
            }
        }
    }
}

// ---------------- column softmax over t (two coalesced passes) ----------------
// S: [16][1024][1024] bf16 (one batch). part: [16][16][1024] fp32 partial sums.
__global__ __launch_bounds__(256) void colpart_k(const u16* __restrict__ S, float* __restrict__ part) {
    int h = blockIdx.y;
    int sc = blockIdx.x & 1;
    int tc = blockIdx.x >> 1;
    int s = sc * 512 + threadIdx.x * 2;
    const u16* base = S + (long)h * 1048576 + (long)tc * 65536 + s;
    float s0 = 0.f, s1 = 0.f;
    #pragma unroll 8
    for (int t = 0; t < 64; ++t) {
        unsigned int u = *reinterpret_cast<const unsigned int*>(base + (long)t * 1024);
        s0 += __expf(bf2f((u16)(u & 0xffff)));
        s1 += __expf(bf2f((u16)(u >> 16)));
    }
    float2 w; w.x = s0; w.y = s1;
    *reinterpret_cast<float2*>(&part[((long)h * 16 + tc) * 1024 + s]) = w;
}

__global__ __launch_bounds__(256) void colnorm_k(u16* __restrict__ S, const float* __restrict__ part) {
    int h = blockIdx.y;
    int sc = blockIdx.x & 1;
    int tc = blockIdx.x >> 1;
    int s = sc * 512 + threadIdx.x * 2;
    float s0 = 0.f, s1 = 0.f;
    #pragma unroll
    for (int i = 0; i < 16; ++i) {
        float2 w = *reinterpret_cast<const float2*>(&part[((long)h * 16 + i) * 1024 + s]);
        s0 += w.x; s1 += w.y;
    }
    float i0 = 1.f / s0, i1 = 1.f / s1;
    u16* base = S + (long)h * 1048576 + (long)tc * 65536 + s;
    #pragma unroll 8
    for (int t = 0; t < 64; ++t) {
        unsigned int u = *reinterpret_cast<unsigned int*>(base + (long)t * 1024);
        float a = __expf(bf2f((u16)(u & 0xffff))) * i0;
        float b = __expf(bf2f((u16)(u >> 16))) * i1;
        *reinterpret_cast<unsigned int*>(base + (long)t * 1024) = ((unsigned)f2bf(b) << 16) | f2bf(a);
    }
}

// ---------------- out = (a+b) - mean - std (ddof=1), rows of 1024 ----------------
__global__ __launch_bounds__(256) void add_subnorm_k(const float* __restrict__ a, const float* __restrict__ b,
                                                     float* __restrict__ out) {
    __shared__ float sm[8];
    long row = blockIdx.x;
    int tid = threadIdx.x;
    float4 av = reinterpret_cast<const float4*>(a + row * 1024)[tid];
    float4 bv = reinterpret_cast<const float4*>(b + row * 1024)[tid];
    float x0 = av.x + bv.x, x1 = av.y + bv.y, x2 = av.z + bv.z, x3 = av.w + bv.w;
    float s = x0 + x1 + x2 + x3;
    for (int o = 32; o > 0; o >>= 1) s += __shfl_down(s, o, 64);
    int lane = tid & 63, w = tid >> 6;
    if (lane == 0) sm[w] = s;
    __syncthreads();
    float mean = (sm[0] + sm[1] + sm[2] + sm[3]) * (1.f / 1024.f);
    float d0 = x0 - mean, d1 = x1 - mean, d2 = x2 - mean, d3 = x3 - mean;
    float q = d0 * d0 + d1 * d1 + d2 * d2 + d3 * d3;
    for (int o = 32; o > 0; o >>= 1) q += __shfl_down(q, o, 64);
    if (lane == 0) sm[w + 4] = q;
    __syncthreads();
    float sd = sqrtf((sm[4] + sm[5] + sm[6] + sm[7]) * (1.f / 1023.f));
    float4 ov;
    ov.x = d0 - sd; ov.y = d1 - sd; ov.z = d2 - sd; ov.w = d3 - sd;
    reinterpret_cast<float4*>(out + row * 1024)[tid] = ov;
}

// ---------------- launcher ----------------

extern "C" void kernel_launch(void* const* d_in, const int* in_sizes, int n_in,
                              void* d_out, int out_size, void* d_ws, size_t ws_size,
                              hipStream_t stream) {
    (void)in_sizes; (void)n_in; (void)out_size; (void)ws_size;
    const float* xf   = (const float*)d_in[0];
    const float* yf   = (const float*)d_in[1];
    const float* Wq1  = (const float*)d_in[2];
    const float* Wk1  = (const float*)d_in[3];
    const float* Wv1  = (const float*)d_in[4];
    const float* Wo1  = (const float*)d_in[5];
    const float* Wq2  = (const float*)d_in[6];
    const float* Wk2  = (const float*)d_in[7];
    const float* Wv2  = (const float*)d_in[8];
    const float* Wo2  = (const float*)d_in[9];
    const float* W_in = (const float*)d_in[10];
    const float* b_in = (const float*)d_in[11];
    const float* W_out= (const float*)d_in[12];
    const float* b_out= (const float*)d_in[13];

    // workspace layout (~161 MB)
    char* p = (char*)d_ws;
    auto alloc = [&](size_t bytes) { char* r = p; p += bytes; return r; };
    u16*   yb    = (u16*)alloc(8388608);    // y bf16 (4096x1024)
    u16*   xb    = (u16*)alloc(8388608);    // x bf16
    u16*   W1cat = (u16*)alloc(6291456);    // [Wq1|Wk1|Wv1]^T-packed (3072 x 1024)
    u16*   Wq2t  = (u16*)alloc(2097152);
    u16*   Wkv2t = (u16*)alloc(4194304);
    u16*   Wo1t  = (u16*)alloc(2097152);
    u16*   Wo2t  = (u16*)alloc(2097152);
    u16*   Winb  = (u16*)alloc(8388608);    // W_in (4096 x 1024) = Bt layout
    u16*   Woutb = (u16*)alloc(8388608);    // W_out (1024 x 4096) = Bt layout
    u16*   QKV   = (u16*)alloc(25165824);   // (4096 x 3072): [Q|K|V] per (b,t)
    u16*   Vt    = (u16*)alloc(8388608);    // per b: (1024 hv x 1024 s)
    u16*   Pb    = (u16*)alloc(33554432);   // per b: S/P [16][1024 t][1024 s]; reused as FFN hidden
    float* csum  = (float*)alloc(1048576);  // colsoftmax partials [16][16][1024] fp32
    u16*   part  = (u16*)alloc(8388608);    // attn partial (4096 x 1024) bf16
    float* gout  = (float*)alloc(16777216); // fp32 gemm out
    float* out1  = (float*)alloc(16777216);
    float* out2d = (float*)d_out;

    // ---- converts + weight packs ----
    convert_f2b_k<<<4096, 256, 0, stream>>>(yf, yb);
    convert_f2b_k<<<4096, 256, 0, stream>>>(xf, xb);
    pack_perm_k<<<4096, 256, 0, stream>>>(Wq1, W1cat,           1024, 64);
    pack_perm_k<<<4096, 256, 0, stream>>>(Wk1, W1cat + 1048576, 1024, 64);
    pack_perm_k<<<4096, 256, 0, stream>>>(Wv1, W1cat + 2097152, 1024, 64);
    pack_perm_k<<<4096, 256, 0, stream>>>(Wq2, Wq2t,            1024, 64);
    pack_perm_k<<<4096, 256, 0, stream>>>(Wk2, Wkv2t,           1024, 64);
    pack_perm_k<<<4096, 256, 0, stream>>>(Wv2, Wkv2t + 1048576, 1024, 64);
    pack_perm_k<<<4096, 256, 0, stream>>>(Wo1, Wo1t,            1024, 1024);
    pack_perm_k<<<4096, 256, 0, stream>>>(Wo2, Wo2t,            1024, 1024);
    convert_f2b_k<<<4096, 256, 0, stream>>>(W_in,  Winb);
    convert_f2b_k<<<4096, 256, 0, stream>>>(W_out, Woutb);

    // attention core for one MHA (QKV buffer already populated)
    auto run_attention = [&](u16* qkv) {
        // V^T per batch: Vt[b][h*64+v][s]
        transpose_k<<<dim3(16, 16, 4), 256, 0, stream>>>(qkv + 2048, 3072L, 3145728L, Vt, 1024L, 1048576L);
        for (int b = 0; b < 4; ++b) {
            const u16* Qb = qkv + (long)b * 3145728;           // cols 0..1023
            const u16* Kb = qkv + (long)b * 3145728 + 1024;    // cols 1024..2047
            // S[h][t][s] = (Q K^T)/8, bf16
            gemm_k<128,128,64,2,2,1,0,0><<<dim3(8, 8, 16), 256, 0, stream>>>(
                Qb, 3072L, 64L, 0L, Kb, 3072L, 64L, 0L,
                (void*)Pb, 1024L, 1048576L, 0L, 16, 64, 0.125f, nullptr);
            // column softmax over t (two passes, coalesced)
            colpart_k<<<dim3(32, 16), 256, 0, stream>>>(Pb, csum);
            colnorm_k<<<dim3(32, 16), 256, 0, stream>>>(Pb, csum);
            // partial[b,t,h*64+v] = sum_s P[t][s] * Vt[h*64+v][s]
            gemm_k<64,64,64,2,2,1,0,0><<<dim3(1, 16, 16), 256, 0, stream>>>(
                Pb, 1024L, 1048576L, 0L, Vt + (long)b * 1048576, 1024L, 65536L, 0L,
                (void*)(part + (long)b * 1048576), 1024L, 64L, 0L, 16, 1024, 1.0f, nullptr);
        }
    };

    // ---- MHA1 (self-attn on y) ----
    gemm_k<128,128,64,2,2,1,0,4><<<dim3(24 * 32), 256, 0, stream>>>(
        yb, 1024L, 0L, 0L, W1cat, 1024L, 0L, 0L, (void*)QKV, 3072L, 0L, 0L, 1, 1024, 1.0f, nullptr);
    run_attention(QKV);
    gemm_k<128,64,64,2,2,0,0,4><<<dim3(16 * 32), 256, 0, stream>>>(
        part, 1024L, 0L, 0L, Wo1t, 1024L, 0L, 0L, (void*)gout, 1024L, 0L, 0L, 1, 1024, 1.0f, nullptr);
    add_subnorm_k<<<4096, 256, 0, stream>>>(gout, yf, out1);

    // ---- MHA2 (q from y, k/v from x) ----
    gemm_k<128,64,64,2,2,1,0,4><<<dim3(16 * 32), 256, 0, stream>>>(
        yb, 1024L, 0L, 0L, Wq2t, 1024L, 0L, 0L, (void*)QKV, 3072L, 0L, 0L, 1, 1024, 1.0f, nullptr);
    gemm_k<128,128,64,2,2,1,0,4><<<dim3(16 * 32), 256, 0, stream>>>(
        xb, 1024L, 0L, 0L, Wkv2t, 1024L, 0L, 0L, (void*)(QKV + 1024), 3072L, 0L, 0L, 1, 1024, 1.0f, nullptr);
    run_attention(QKV);
    gemm_k<128,64,64,2,2,0,0,4><<<dim3(16 * 32), 256, 0, stream>>>(
        part, 1024L, 0L, 0L, Wo2t, 1024L, 0L, 0L, (void*)gout, 1024L, 0L, 0L, 1, 1024, 1.0f, nullptr);
    add_subnorm_k<<<4096, 256, 0, stream>>>(gout, out1, out2d);

    // ---- FFN on y (hidden reuses Pb: 4096x4096 bf16) ----
    gemm_k<128,128,64,2,2,1,1,4><<<dim3(32 * 32), 256, 0, stream>>>(
        yb, 1024L, 0L, 0L, Winb, 1024L, 0L, 0L, (void*)Pb, 4096L, 0L, 0L, 1, 1024, 1.0f, b_in);
    gemm_k<128,64,64,2,2,0,2,4><<<dim3(16 * 32), 256, 0, stream>>>(
        Pb, 4096L, 0L, 0L, Woutb, 4096L, 0L, 0L, (void*)gout, 1024L, 0L, 0L, 1, 4096, 1.0f, b_out);
    add_subnorm_k<<<4096, 256, 0, stream>>>(gout, (const float*)d_out, (float*)d_out);
}

// Round 5
// 640.186 us; speedup vs baseline: 3.2760x; 1.2712x over previous
//
#include <hip/hip_runtime.h>

// DecoderStack: B=4,T=1024,D=1024,H=16,DK=DV=64,FF=4096
// Faithful quirks: softmax over QUERY axis (column softmax over t) — done as
// E=exp(S) in scores epilogue + column sums l_s via atomics + V scaled by 1/l_s;
// sub_norm(o) = o - mean - std (ddof=1).
// bf16 MFMA 16x16x32, fp32 accumulate, global_load_lds staging, XOR-swizzled
// LDS, XCD-slab block swizzle, split-K (reduce folded into add_subnorm).

typedef unsigned short u16;
typedef __bf16 bf16x8 __attribute__((ext_vector_type(8)));
typedef float f32x4 __attribute__((ext_vector_type(4)));

__device__ __forceinline__ u16 f2bf(float f) {
    unsigned int u = __float_as_uint(f);
    u += 0x7fffu + ((u >> 16) & 1u);   // RNE; inputs are finite
    return (u16)(u >> 16);
}
__device__ __forceinline__ float bf2f(u16 b) {
    return __uint_as_float(((unsigned int)b) << 16);
}

typedef __attribute__((address_space(1))) const void* as1cv;
typedef __attribute__((address_space(3))) void* as3v;
__device__ __forceinline__ void gl_lds16(const void* g, void* l) {
    __builtin_amdgcn_global_load_lds((as1cv)g, (as3v)l, 16, 0, 0);
}

// ---------------- converts / packs ----------------

__global__ __launch_bounds__(256) void convert_f2b_k(const float* __restrict__ in, u16* __restrict__ out) {
    long i = (long)blockIdx.x * 256 + threadIdx.x;
    float4 v = reinterpret_cast<const float4*>(in)[i];
    ushort4 o;
    o.x = f2bf(v.x); o.y = f2bf(v.y); o.z = f2bf(v.z); o.w = f2bf(v.w);
    reinterpret_cast<ushort4*>(out)[i] = o;
}

// out[p][r][q] = in[p][q][r] (fp32->bf16), LDS-tiled so both sides coalesce.
// grid (R/64, Q/64, P)
__global__ __launch_bounds__(256) void pack_perm_t(const float* __restrict__ in, u16* __restrict__ out,
                                                   int Q, int R) {
    __shared__ float tile[64][65];
    int p = blockIdx.z;
    int r0 = blockIdx.x * 64, q0 = blockIdx.y * 64;
    int tx = threadIdx.x & 63, ty = threadIdx.x >> 6;
    const float* inp = in + ((long)p * Q + q0) * R + r0;
    #pragma unroll
    for (int i = 0; i < 64; i += 4)
        tile[ty + i][tx] = inp[(long)(ty + i) * R + tx];
    __syncthreads();
    u16* outp = out + ((long)p * R + r0) * Q + q0;
    #pragma unroll
    for (int i = 0; i < 64; i += 4)
        outp[(long)(ty + i) * Q + tx] = f2bf(tile[tx][ty + i]);
}

// 64x64 tiled bf16 transpose: out[c][r] = in[r][c], batched over z
__global__ __launch_bounds__(256) void transpose_k(const u16* __restrict__ in, long ld_in, long z_in,
                                                   u16* __restrict__ out, long ld_out, long z_out) {
    __shared__ u16 tile[64][66];
    const u16* inz = in + (long)blockIdx.z * z_in;
    u16* outz = out + (long)blockIdx.z * z_out;
    int r0 = blockIdx.y * 64;
    int c0 = blockIdx.x * 64;
    int tx = threadIdx.x & 63, ty = threadIdx.x >> 6;
    #pragma unroll
    for (int i = 0; i < 64; i += 4)
        tile[ty + i][tx] = inz[(long)(r0 + ty + i) * ld_in + c0 + tx];
    __syncthreads();
    #pragma unroll
    for (int i = 0; i < 64; i += 4)
        outz[(long)(c0 + ty + i) * ld_out + r0 + tx] = tile[tx][ty + i];
}

// ---------------- GEMM: C[M][N] = alpha * A[M][K] x Bt[N][K]^T ----------------
// LDS XOR-swizzled. SWZ=0: 3D grid (x,y,z=batch). SWZ=4: 1D grid, XCD-slab
// mapping my=(L&7)*4+((L>>3)&3), mx=L>>5; KS>1: split-K chunks (requires
// nx=16,ny=32 => 512 blocks/chunk), chunk = L>>9, offsets via *_zout params.
// EPI: 0 none, 1 +bias+relu, 2 +bias, 3 exp + atomic column-sum into csum.
template<int BM, int BN, int BK, int WM, int WN, int OUT_BF16, int EPI, int SWZ, int KS>
__global__ __launch_bounds__(256) void gemm_k(
    const u16* __restrict__ A, long lda, long a_zin, long a_zout,
    const u16* __restrict__ B, long ldb, long b_zin, long b_zout,
    void* __restrict__ Cv, long ldc, long c_zin, long c_zout,
    int zin, int K, float alpha, const float* __restrict__ bias,
    float* __restrict__ csum)
{
    static_assert(BK == 64, "staging assumes BK=64");
    constexpr int WTM = BM / WM;
    constexpr int WTN = BN / WN;
    constexpr int TM = WTM / 16;
    constexpr int TN = WTN / 16;
    __shared__ __align__(16) u16 As[BM * BK];
    __shared__ __align__(16) u16 Bs[BN * BK];

    int bx, by, z;
    if (SWZ) {
        int L = blockIdx.x;
        if (KS > 1) { z = L >> 9; L &= 511; } else { z = 0; }
        by = (L & 7) * SWZ + ((L >> 3) & (SWZ - 1));
        bx = L >> 5;
    } else {
        bx = blockIdx.x; by = blockIdx.y; z = blockIdx.z;
    }
    int zi = z % zin, zo = z / zin;
    A += (long)zi * a_zin + (long)zo * a_zout;
    B += (long)zi * b_zin + (long)zo * b_zout;
    long coff = (long)zi * c_zin + (long)zo * c_zout;

    int tid = threadIdx.x;
    int lane = tid & 63;
    int wave = tid >> 6;
    int wm = wave / WN, wn = wave % WN;
    long bm0 = (long)by * BM, bn0 = (long)bx * BN;

    f32x4 acc[TM][TN];
    #pragma unroll
    for (int i = 0; i < TM; ++i)
        #pragma unroll
        for (int j = 0; j < TN; ++j) {
            acc[i][j][0] = 0.f; acc[i][j][1] = 0.f;
            acc[i][j][2] = 0.f; acc[i][j][3] = 0.f;
        }

    int r16 = lane & 15;
    int quad = lane >> 4;
    int l8 = lane >> 3;                    // stripe row
    int gsw = ((lane & 7) ^ l8) * 8;       // swizzled global col (elements)

    constexpr int ASTR = BM / 8;
    constexpr int BSTR = BN / 8;

    for (int k0 = 0; k0 < K; k0 += BK) {
        #pragma unroll
        for (int s = wave; s < ASTR; s += 4)
            gl_lds16(&A[(bm0 + s * 8 + l8) * lda + k0 + gsw], &As[s * 512]);
        #pragma unroll
        for (int s = wave; s < BSTR; s += 4)
            gl_lds16(&B[(bn0 + s * 8 + l8) * ldb + k0 + gsw], &Bs[s * 512]);
        __syncthreads();
        #pragma unroll
        for (int kk = 0; kk < BK; kk += 32) {
            int cb = (kk >> 3) + quad;
            bf16x8 av[TM], bv[TN];
            #pragma unroll
            for (int i = 0; i < TM; ++i) {
                int r = wm * WTM + i * 16 + r16;
                av[i] = *reinterpret_cast<const bf16x8*>(&As[r * 64 + ((cb ^ (r & 7)) * 8)]);
            }
            #pragma unroll
            for (int j = 0; j < TN; ++j) {
                int r = wn * WTN + j * 16 + r16;
                bv[j] = *reinterpret_cast<const bf16x8*>(&Bs[r * 64 + ((cb ^ (r & 7)) * 8)]);
            }
            #pragma unroll
            for (int i = 0; i < TM; ++i)
                #pragma unroll
                for (int j = 0; j < TN; ++j)
                    acc[i][j] = __builtin_amdgcn_mfma_f32_16x16x32_bf16(av[i], bv[j], acc[i][j], 0, 0, 0);
        }
        __syncthreads();
    }

    // epilogue: C/D frag is col=lane&15, row=quad*4+reg (verified m89/m91)
    int rb = quad * 4;
    float csl[TN];
    #pragma unroll
    for (int j = 0; j < TN; ++j) csl[j] = 0.f;
    #pragma unroll
    for (int i = 0; i < TM; ++i) {
        #pragma unroll
        for (int j = 0; j < TN; ++j) {
            long col = bn0 + wn * WTN + j * 16 + r16;
            float bsv = (EPI == 1 || EPI == 2) ? bias[col] : 0.f;
            #pragma unroll
            for (int r = 0; r < 4; ++r) {
                long row = bm0 + wm * WTM + i * 16 + rb + r;
                float v = acc[i][j][r] * alpha;
                if (EPI == 1) { v += bsv; v = v > 0.f ? v : 0.f; }
                else if (EPI == 2) { v += bsv; }
                else if (EPI == 3) { v = __expf(v); csl[j] += v; }
                long idx = coff + row * ldc + col;
                if (OUT_BF16) reinterpret_cast<u16*>(Cv)[idx] = f2bf(v);
                else          reinterpret_cast<float*>(Cv)[idx] = v;
            }
        }
    }
    if (EPI == 3) {
        // reduce the wave's 64 rows per column (4 quads) then one atomic per col
        #pragma unroll
        for (int j = 0; j < TN; ++j) {
            float cs = csl[j];
            cs += __shfl_xor(cs, 16, 64);
            cs += __shfl_xor(cs, 32, 64);
            if (quad == 0) {
                long col = bn0 + wn * WTN + j * 16 + r16;
                atomicAdd(&csum[(long)zi * 1024 + col], cs);
            }
        }
    }
}

// ---------------- Vt *= 1/l : Vt slab [1024 hv][1024 s], csum [16][1024] ----------------
__global__ __launch_bounds__(256) void vscale_k(u16* __restrict__ Vt, const float* __restrict__ csum) {
    long idx = (long)blockIdx.x * 256 + threadIdx.x;   // grid 512
    int hv = (int)(idx >> 7);
    int s8 = ((int)idx & 127) * 8;
    const float* cs = csum + (hv >> 6) * 1024 + s8;
    u16* pv = Vt + (long)hv * 1024 + s8;
    ushort4 a = *reinterpret_cast<ushort4*>(pv);
    ushort4 b = *reinterpret_cast<ushort4*>(pv + 4);
    a.x = f2bf(bf2f(a.x) / cs[0]); a.y = f2bf(bf2f(a.y) / cs[1]);
    a.z = f2bf(bf2f(a.z) / cs[2]); a.w = f2bf(bf2f(a.w) / cs[3]);
    b.x = f2bf(bf2f(b.x) / cs[4]); b.y = f2bf(bf2f(b.y) / cs[5]);
    b.z = f2bf(bf2f(b.z) / cs[6]); b.w = f2bf(bf2f(b.w) / cs[7]);
    *reinterpret_cast<ushort4*>(pv) = a;
    *reinterpret_cast<ushort4*>(pv + 4) = b;
}

// ---------------- out = (sum of NP partial slabs + resid [+bias]) - mean - std ----------------
template<int NP, int BIAS>
__global__ __launch_bounds__(256) void addsn_k(const float* __restrict__ parts, long pstride,
                                               const float* __restrict__ resid,
                                               const float* __restrict__ bias,
                                               float* __restrict__ out) {
    __shared__ float sm[8];
    long row = blockIdx.x;
    int tid = threadIdx.x;
    float4 x = reinterpret_cast<const float4*>(resid + row * 1024)[tid];
    #pragma unroll
    for (int p = 0; p < NP; ++p) {
        float4 a = reinterpret_cast<const float4*>(parts + p * pstride + row * 1024)[tid];
        x.x += a.x; x.y += a.y; x.z += a.z; x.w += a.w;
    }
    if (BIAS) {
        float4 bb = reinterpret_cast<const float4*>(bias)[tid];
        x.x += bb.x; x.y += bb.y; x.z += bb.z; x.w += bb.w;
    }
    float s = x.x + x.y + x.z + x.w;
    for (int o = 32; o > 0; o >>= 1) s += __shfl_down(s, o, 64);
    int lane = tid & 63, w = tid >> 6;
    if (lane == 0) sm[w] = s;
    __syncthreads();
    float mean = (sm[0] + sm[1] + sm[2] + sm[3]) * (1.f / 1024.f);
    float d0 = x.x - mean, d1 = x.y - mean, d2 = x.z - mean, d3 = x.w - mean;
    float q = d0 * d0 + d1 * d1 + d2 * d2 + d3 * d3;
    for (int o = 32; o > 0; o >>= 1) q += __shfl_down(q, o, 64);
    if (lane == 0) sm[w + 4] = q;
    __syncthreads();
    float sd = sqrtf((sm[4] + sm[5] + sm[6] + sm[7]) * (1.f / 1023.f));
    float4 ov;
    ov.x = d0 - sd; ov.y = d1 - sd; ov.z = d2 - sd; ov.w = d3 - sd;
    reinterpret_cast<float4*>(out + row * 1024)[tid] = ov;
}

// ---------------- launcher ----------------

extern "C" void kernel_launch(void* const* d_in, const int* in_sizes, int n_in,
                              void* d_out, int out_size, void* d_ws, size_t ws_size,
                              hipStream_t stream) {
    (void)in_sizes; (void)n_in; (void)out_size; (void)ws_size;
    const float* xf   = (const float*)d_in[0];
    const float* yf   = (const float*)d_in[1];
    const float* Wq1  = (const float*)d_in[2];
    const float* Wk1  = (const float*)d_in[3];
    const float* Wv1  = (const float*)d_in[4];
    const float* Wo1  = (const float*)d_in[5];
    const float* Wq2  = (const float*)d_in[6];
    const float* Wk2  = (const float*)d_in[7];
    const float* Wv2  = (const float*)d_in[8];
    const float* Wo2  = (const float*)d_in[9];
    const float* W_in = (const float*)d_in[10];
    const float* b_in = (const float*)d_in[11];
    const float* W_out= (const float*)d_in[12];
    const float* b_out= (const float*)d_in[13];

    // workspace layout (~192 MB)
    char* p = (char*)d_ws;
    auto alloc = [&](size_t bytes) { char* r = p; p += bytes; return r; };
    u16*   yb    = (u16*)alloc(8388608);    // y bf16 (4096x1024)
    u16*   xb    = (u16*)alloc(8388608);    // x bf16
    u16*   W1cat = (u16*)alloc(8388608);    // [Wq1|Wk1|Wv1|Wq2]^T-packed (4096 x 1024)
    u16*   Wkv2t = (u16*)alloc(4194304);    // [Wk2|Wv2] (2048 x 1024)
    u16*   Wo1t  = (u16*)alloc(2097152);
    u16*   Wo2t  = (u16*)alloc(2097152);
    u16*   Winb  = (u16*)alloc(8388608);    // W_in (4096 x 1024) = Bt layout
    u16*   Woutb = (u16*)alloc(8388608);    // W_out (1024 x 4096) = Bt layout
    u16*   QKV   = (u16*)alloc(33554432);   // (4096 x 4096): [Q1|K1|V1|Q2] per (b,t)
    u16*   KV2   = (u16*)alloc(16777216);   // (4096 x 2048): [K2|V2]
    u16*   Vt    = (u16*)alloc(8388608);    // per b: (1024 hv x 1024 s), scaled by 1/l in place
    u16*   Pb    = (u16*)alloc(33554432);   // per b: E=exp(S) [16][1024 t][1024 s]; reused as FFN hidden
    float* csum  = (float*)alloc(65536);    // column sums l_s [16][1024]
    u16*   part  = (u16*)alloc(8388608);    // attn partial (4096 x 1024) bf16
    float* gout  = (float*)alloc(33554432); // fp32 split-K partials, 2 slabs of 16 MB
    float* out1  = (float*)alloc(16777216);

    // ---- converts + weight packs ----
    convert_f2b_k<<<4096, 256, 0, stream>>>(yf, yb);
    convert_f2b_k<<<4096, 256, 0, stream>>>(xf, xb);
    pack_perm_t<<<dim3(1, 16, 16), 256, 0, stream>>>(Wq1, W1cat,           1024, 64);
    pack_perm_t<<<dim3(1, 16, 16), 256, 0, stream>>>(Wk1, W1cat + 1048576, 1024, 64);
    pack_perm_t<<<dim3(1, 16, 16), 256, 0, stream>>>(Wv1, W1cat + 2097152, 1024, 64);
    pack_perm_t<<<dim3(1, 16, 16), 256, 0, stream>>>(Wq2, W1cat + 3145728, 1024, 64);
    pack_perm_t<<<dim3(1, 16, 16), 256, 0, stream>>>(Wk2, Wkv2t,           1024, 64);
    pack_perm_t<<<dim3(1, 16, 16), 256, 0, stream>>>(Wv2, Wkv2t + 1048576, 1024, 64);
    pack_perm_t<<<dim3(16, 16, 1), 256, 0, stream>>>(Wo1, Wo1t,            1024, 1024);
    pack_perm_t<<<dim3(16, 16, 1), 256, 0, stream>>>(Wo2, Wo2t,            1024, 1024);
    convert_f2b_k<<<4096, 256, 0, stream>>>(W_in,  Winb);
    convert_f2b_k<<<4096, 256, 0, stream>>>(W_out, Woutb);

    // attention core: E=exp(QK^T/8) + atomic l_s; Vt scaled by 1/l_s; PV.
    auto run_attention = [&](const u16* Q, long ldq, long qz,
                             const u16* Kp, long ldk, long kz,
                             const u16* Vp, long ldv, long vz) {
        transpose_k<<<dim3(16, 16, 4), 256, 0, stream>>>(Vp, ldv, vz, Vt, 1024L, 1048576L);
        for (int b = 0; b < 4; ++b) {
            hipMemsetAsync(csum, 0, 65536, stream);
            gemm_k<128,128,64,2,2,1,3,0,1><<<dim3(8, 8, 16), 256, 0, stream>>>(
                Q + b * qz, ldq, 64L, 0L, Kp + b * kz, ldk, 64L, 0L,
                (void*)Pb, 1024L, 1048576L, 0L, 16, 64, 0.125f, nullptr, csum);
            vscale_k<<<512, 256, 0, stream>>>(Vt + (long)b * 1048576, csum);
            gemm_k<64,64,64,2,2,1,0,0,1><<<dim3(1, 16, 16), 256, 0, stream>>>(
                Pb, 1024L, 1048576L, 0L, Vt + (long)b * 1048576, 1024L, 65536L, 0L,
                (void*)(part + (long)b * 1048576), 1024L, 64L, 0L, 16, 1024, 1.0f, nullptr, nullptr);
        }
    };

    // ---- fused projections: QKV1 + Q2 (both consume y), N=4096 ----
    gemm_k<128,128,64,2,2,1,0,4,1><<<dim3(32 * 32), 256, 0, stream>>>(
        yb, 1024L, 0L, 0L, W1cat, 1024L, 0L, 0L, (void*)QKV, 4096L, 0L, 0L, 1, 1024, 1.0f, nullptr, nullptr);
    // K2/V2 from x, N=2048
    gemm_k<128,128,64,2,2,1,0,4,1><<<dim3(16 * 32), 256, 0, stream>>>(
        xb, 1024L, 0L, 0L, Wkv2t, 1024L, 0L, 0L, (void*)KV2, 2048L, 0L, 0L, 1, 1024, 1.0f, nullptr, nullptr);

    // ---- MHA1 (self-attn on y): Q/K/V at cols 0/1024/2048 of QKV ----
    run_attention(QKV, 4096L, 4194304L, QKV + 1024, 4096L, 4194304L, QKV + 2048, 4096L, 4194304L);
    gemm_k<128,64,64,2,2,0,0,4,2><<<dim3(2 * 512), 256, 0, stream>>>(
        part, 1024L, 0L, 512L, Wo1t, 1024L, 0L, 512L,
        (void*)gout, 1024L, 0L, 4194304L, 1, 512, 1.0f, nullptr, nullptr);
    addsn_k<2,0><<<4096, 256, 0, stream>>>(gout, 4194304L, yf, nullptr, out1);

    // ---- MHA2 (q from y at QKV col 3072; k/v from x in KV2) ----
    run_attention(QKV + 3072, 4096L, 4194304L, KV2, 2048L, 2097152L, KV2 + 1024, 2048L, 2097152L);
    gemm_k<128,64,64,2,2,0,0,4,2><<<dim3(2 * 512), 256, 0, stream>>>(
        part, 1024L, 0L, 512L, Wo2t, 1024L, 0L, 512L,
        (void*)gout, 1024L, 0L, 4194304L, 1, 512, 1.0f, nullptr, nullptr);
    addsn_k<2,0><<<4096, 256, 0, stream>>>(gout, 4194304L, out1, nullptr, (float*)d_out);

    // ---- FFN on y (hidden reuses Pb: 4096x4096 bf16) ----
    gemm_k<128,128,64,2,2,1,1,4,1><<<dim3(32 * 32), 256, 0, stream>>>(
        yb, 1024L, 0L, 0L, Winb, 1024L, 0L, 0L, (void*)Pb, 4096L, 0L, 0L, 1, 1024, 1.0f, b_in, nullptr);
    gemm_k<128,64,64,2,2,0,0,4,2><<<dim3(2 * 512), 256, 0, stream>>>(
        Pb, 4096L, 0L, 2048L, Woutb, 4096L, 0L, 2048L,
        (void*)gout, 1024L, 0L, 4194304L, 1, 2048, 1.0f, nullptr, nullptr);
    addsn_k<2,1><<<4096, 256, 0, stream>>>(gout, 4194304L, (const float*)d_out, b_out, (float*)d_out);
}